// Round 1
// baseline (503.202 us; speedup 1.0000x reference)
//
#include <hip/hip_runtime.h>
#include <math.h>

// MoE FFN, dense-as-3-GEMMs formulation:
//   T = (X @ W1cat) * mw   [8192 x 2048] bf16
//   Hb = gelu(T @ W2flat)  [8192 x 4096] bf16
//   out = Hb @ lin2_w^T + b  [8192 x 1024] f32
// Router (top-2 of softmax) computed in f64 to protect selection vs np ref.

using short8  = __attribute__((ext_vector_type(8))) short;   // 8 bf16 in 4 VGPRs
using floatx4 = __attribute__((ext_vector_type(4))) float;   // MFMA accumulator
typedef unsigned short bf16_t;

#define TOK   8192   // B*S
#define HDIM  1024
#define RDIM  256
#define FDIM  4096
#define NEXP  8

__device__ __forceinline__ bf16_t f2bf(float f) {
  union { float f; unsigned u; } a; a.f = f;
  unsigned u = a.u;
  return (bf16_t)((u + 0x7FFFu + ((u >> 16) & 1u)) >> 16);  // RNE
}

__device__ __forceinline__ void gload16(const void* g, void* l) {
  // async global->LDS, 16B per lane; LDS dest = wave-uniform base + lane*16
  __builtin_amdgcn_global_load_lds(
      (const __attribute__((address_space(1))) void*)g,
      (__attribute__((address_space(3))) void*)l, 16, 0, 0);
}

// ---------------------------------------------------------------- converts

__global__ void cvt_x(const float* __restrict__ in, bf16_t* __restrict__ out) {
  const size_t i = ((size_t)blockIdx.x * 256 + threadIdx.x) * 4;
  float4 v = *(const float4*)(in + i);
  ushort4 pk;
  pk.x = f2bf(v.x); pk.y = f2bf(v.y); pk.z = f2bf(v.z); pk.w = f2bf(v.w);
  *(ushort4*)(out + i) = pk;
}

// transpose+convert: in f32 [rows][cols] (slice z at in + z*inSlice)
// out[( c + z*outRowStep )*ldo + z*outColStep + r] = in[r][c]  (bf16)
__global__ void tcvt(const float* __restrict__ in, bf16_t* __restrict__ out,
                     int cols, size_t inSlice, size_t ldo,
                     int outRowStep, int outColStep) {
  __shared__ float tile[32][33];
  const int z  = blockIdx.z;
  const float* src = in + (size_t)z * inSlice;
  const int c0 = blockIdx.x * 32;
  const int r0 = blockIdx.y * 32;
  const int tx = threadIdx.x;  // 0..31
  const int ty = threadIdx.y;  // 0..7
#pragma unroll
  for (int i = 0; i < 32; i += 8)
    tile[ty + i][tx] = src[(size_t)(r0 + ty + i) * cols + (c0 + tx)];
  __syncthreads();
#pragma unroll
  for (int i = 0; i < 32; i += 8) {
    float v = tile[tx][ty + i];
    out[((size_t)(c0 + ty + i) + (size_t)z * outRowStep) * ldo +
        (size_t)z * outColStep + (r0 + tx)] = f2bf(v);
  }
}

// ---------------------------------------------------------------- router

__global__ void router_kernel(const float* __restrict__ x,
                              const float* __restrict__ rw,
                              const float* __restrict__ rb,
                              float* __restrict__ mw) {
  const int token = blockIdx.x * 4 + (threadIdx.x >> 6);
  const int lane  = threadIdx.x & 63;
  const float* xr = x + (size_t)token * HDIM;

  double acc[NEXP];
#pragma unroll
  for (int e = 0; e < NEXP; e++) acc[e] = 0.0;

  for (int h = lane; h < HDIM; h += 64) {
    double xv = (double)xr[h];
    const float* wr = rw + (size_t)h * NEXP;
#pragma unroll
    for (int e = 0; e < NEXP; e++) acc[e] += xv * (double)wr[e];
  }
#pragma unroll
  for (int off = 32; off > 0; off >>= 1) {
#pragma unroll
    for (int e = 0; e < NEXP; e++) acc[e] += __shfl_xor(acc[e], off, 64);
  }
  double lg[NEXP];
#pragma unroll
  for (int e = 0; e < NEXP; e++) lg[e] = acc[e] + (double)rb[e];

  double mx = lg[0];
#pragma unroll
  for (int e = 1; e < NEXP; e++) mx = fmax(mx, lg[e]);
  double p[NEXP]; double den = 0.0;
#pragma unroll
  for (int e = 0; e < NEXP; e++) { p[e] = exp(lg[e] - mx); den += p[e]; }

  // top-2, ties -> lower index (lax.top_k semantics)
  int i1 = 0;
#pragma unroll
  for (int e = 1; e < NEXP; e++) if (lg[e] > lg[i1]) i1 = e;
  int i2 = (i1 == 0) ? 1 : 0;
#pragma unroll
  for (int e = 0; e < NEXP; e++)
    if (e != i1 && e != i2 && lg[e] > lg[i2]) i2 = e;

  if (lane < NEXP) {
    float o = 0.f;
    if (lane == i1 || lane == i2) o = (float)(p[lane] / den);
    mw[(size_t)token * NEXP + lane] = o;
  }
}

// ---------------------------------------------------------------- GEMM (B^T)

// C[M,N] = A[M,K] @ Bt[N,K]^T ; 128x128 tile, BK=32, 4 waves 2x2, 4x4 MFMA/wave
// EPI 0: *mw -> bf16 ; EPI 1: gelu_erf -> bf16 ; EPI 2: +bias -> f32
template <int EPI>
__global__ __launch_bounds__(256)
void gemm_bt(const bf16_t* __restrict__ A, const bf16_t* __restrict__ Bt,
             void* __restrict__ Cout, const float* __restrict__ epi,
             int M, int N, int K) {
  __shared__ bf16_t As[128 * 32];
  __shared__ bf16_t Bs[128 * 32];
  const int tid  = threadIdx.x;
  const int lane = tid & 63;
  const int w    = tid >> 6;
  const int m0 = blockIdx.y * 128;
  const int n0 = blockIdx.x * 128;
  const int wm = (w >> 1) * 64;
  const int wn = (w & 1) * 64;
  const int l16  = lane & 15;
  const int quad = lane >> 4;

  floatx4 acc[4][4];
  const floatx4 zero = {0.f, 0.f, 0.f, 0.f};
#pragma unroll
  for (int i = 0; i < 4; i++)
#pragma unroll
    for (int j = 0; j < 4; j++) acc[i][j] = zero;

  // staging: each wave fills 2 x 1KB chunks of A tile and of B tile.
  // chunk c covers tile rows 16c..16c+15; lane l -> row 16c + l/4, 16B col (l%4)
  const bf16_t* ga = A + (size_t)(m0 + w * 32 + (lane >> 2)) * K + (lane & 3) * 8;
  const bf16_t* gb = Bt + (size_t)(n0 + w * 32 + (lane >> 2)) * K + (lane & 3) * 8;
  bf16_t* lA0 = &As[w * 1024];
  bf16_t* lA1 = &As[w * 1024 + 512];
  bf16_t* lB0 = &Bs[w * 1024];
  bf16_t* lB1 = &Bs[w * 1024 + 512];

  for (int k0 = 0; k0 < K; k0 += 32) {
    __syncthreads();  // previous iter's LDS reads done
    gload16(ga, lA0);
    gload16(ga + (size_t)16 * K, lA1);
    gload16(gb, lB0);
    gload16(gb + (size_t)16 * K, lB1);
    ga += 32; gb += 32;
    __syncthreads();  // staging complete (vmcnt drained at barrier)

    short8 af[4], bfr[4];
#pragma unroll
    for (int i = 0; i < 4; i++)
      af[i] = *(const short8*)&As[(wm + i * 16 + l16) * 32 + quad * 8];
#pragma unroll
    for (int i = 0; i < 4; i++)
      bfr[i] = *(const short8*)&Bs[(wn + i * 16 + l16) * 32 + quad * 8];
#pragma unroll
    for (int mi = 0; mi < 4; mi++)
#pragma unroll
      for (int ni = 0; ni < 4; ni++)
        acc[mi][ni] = __builtin_amdgcn_mfma_f32_16x16x32_bf16(
            af[mi], bfr[ni], acc[mi][ni], 0, 0, 0);
  }

  // epilogue: C/D layout col = lane&15, row = quad*4 + r
#pragma unroll
  for (int mi = 0; mi < 4; mi++) {
#pragma unroll
    for (int ni = 0; ni < 4; ni++) {
      const int row = m0 + wm + mi * 16 + quad * 4;
      const int col = n0 + wn + ni * 16 + l16;
#pragma unroll
      for (int r = 0; r < 4; r++) {
        float v = acc[mi][ni][r];
        if (EPI == 0) {
          float s = epi[(size_t)(row + r) * NEXP + (col >> 8)];
          ((bf16_t*)Cout)[(size_t)(row + r) * N + col] = f2bf(v * s);
        } else if (EPI == 1) {
          float g = 0.5f * v * (1.0f + erff(v * 0.70710678118654752f));
          ((bf16_t*)Cout)[(size_t)(row + r) * N + col] = f2bf(g);
        } else {
          ((float*)Cout)[(size_t)(row + r) * N + col] = v + epi[col];
        }
      }
    }
  }
}

// ---------------------------------------------------------------- launch

extern "C" void kernel_launch(void* const* d_in, const int* in_sizes, int n_in,
                              void* d_out, int out_size, void* d_ws, size_t ws_size,
                              hipStream_t stream) {
  const float* x   = (const float*)d_in[0];
  const float* rw  = (const float*)d_in[1];
  const float* rb  = (const float*)d_in[2];
  const float* w1  = (const float*)d_in[3];
  const float* w2  = (const float*)d_in[4];
  const float* l2w = (const float*)d_in[5];
  const float* l2b = (const float*)d_in[6];

  char* ws = (char*)d_ws;
  bf16_t* xb  = (bf16_t*)(ws);                 // 8192x1024 bf16   16,777,216 B
  bf16_t* w1t = (bf16_t*)(ws + 16777216);      // 2048x1024 bf16    4,194,304
  bf16_t* w2t = (bf16_t*)(ws + 20971520);      // 4096x2048 bf16   16,777,216
  bf16_t* ltw = (bf16_t*)(ws + 37748736);      // 1024x4096 bf16    8,388,608
  float*  mw  = (float*) (ws + 46137344);      // 8192x8 f32          262,144
  bf16_t* T   = (bf16_t*)(ws + 46399488);      // 8192x2048 bf16   33,554,432
  bf16_t* Hb  = (bf16_t*)(ws + 79953920);      // 8192x4096 bf16   67,108,864
  // total 147,062,784 bytes

  // prep: bf16 conversions (+ transposes so GEMM gets B^T [N,K])
  cvt_x<<<TOK * HDIM / 1024, 256, 0, stream>>>(x, xb);
  // w1 [E][H][R] -> w1t[e*R + r][h]
  tcvt<<<dim3(RDIM / 32, HDIM / 32, NEXP), dim3(32, 8), 0, stream>>>(
      w1, w1t, RDIM, (size_t)HDIM * RDIM, HDIM, RDIM, 0);
  // w2 [E][R][F] -> w2t[f][e*R + r]
  tcvt<<<dim3(FDIM / 32, RDIM / 32, NEXP), dim3(32, 8), 0, stream>>>(
      w2, w2t, FDIM, (size_t)RDIM * FDIM, 2048, 0, RDIM);
  // lin2_w [F][H] -> ltw[h][f]
  tcvt<<<dim3(HDIM / 32, FDIM / 32, 1), dim3(32, 8), 0, stream>>>(
      l2w, ltw, HDIM, 0, FDIM, 0, 0);

  router_kernel<<<TOK / 4, 256, 0, stream>>>(x, rw, rb, mw);

  // G1: T = (X @ W1cat) * mw    [8192 x 2048], K=1024
  gemm_bt<0><<<dim3(2048 / 128, TOK / 128), 256, 0, stream>>>(
      xb, w1t, T, mw, TOK, 2048, HDIM);
  // G2: Hb = gelu(T @ W2flat)   [8192 x 4096], K=2048
  gemm_bt<1><<<dim3(FDIM / 128, TOK / 128), 256, 0, stream>>>(
      T, w2t, Hb, nullptr, TOK, FDIM, 2048);
  // G3: out = Hb @ lin2_w^T + b [8192 x 1024], K=4096
  gemm_bt<2><<<dim3(HDIM / 128, TOK / 128), 256, 0, stream>>>(
      Hb, ltw, (float*)d_out, l2b, TOK, HDIM, FDIM);
}

// Round 3
// 446.543 us; speedup vs baseline: 1.1269x; 1.1269x over previous
//
#include <hip/hip_runtime.h>
#include <math.h>

// MoE FFN, routed (top-2 pair-grouped) formulation:
//   R1: router top-2 -> (e_lo,e_hi) pair bin per token, probs
//   R2: bin -> 128-aligned slot ranges + tile list ; R3: scatter tokens->slots
//   G1: Tp[slot,512] = X[tok] @ [w1[e_lo]|w1[e_hi]] * (w_lo|w_hi)   (bf16)
//   G2: Hb[tok,4096] = gelu(Tp[slot] @ [w2[e_lo];w2[e_hi]])         (bf16, scatter)
//   G3: out = Hb @ lin2_w^T + b                                     (f32)
// All GEMM LDS tiles XOR-swizzled (granule c^((r>>1)&3)) to kill bank conflicts.

using short8  = __attribute__((ext_vector_type(8))) short;
using floatx4 = __attribute__((ext_vector_type(4))) float;
typedef unsigned short bf16_t;

#define TOK   8192
#define HDIM  1024
#define RDIM  256
#define FDIM  4096
#define NEXP  8
#define MAXTILES 128
#define MAXSLOTS 16384

__device__ __forceinline__ bf16_t f2bf(float f) {
  union { float f; unsigned u; } a; a.f = f;
  unsigned u = a.u;
  return (bf16_t)((u + 0x7FFFu + ((u >> 16) & 1u)) >> 16);  // RNE
}

__device__ __forceinline__ float gelu_erf(float v) {
  return 0.5f * v * (1.0f + erff(v * 0.70710678118654752f));
}

__device__ __forceinline__ void gload16(const void* g, void* l) {
  __builtin_amdgcn_global_load_lds(
      (const __attribute__((address_space(1))) void*)g,
      (__attribute__((address_space(3))) void*)l, 16, 0, 0);
}

// ---------------------------------------------------------------- converts

__global__ void cvt_x(const float* __restrict__ in, bf16_t* __restrict__ out) {
  const size_t i = ((size_t)blockIdx.x * 256 + threadIdx.x) * 4;
  float4 v = *(const float4*)(in + i);
  ushort4 pk;
  pk.x = f2bf(v.x); pk.y = f2bf(v.y); pk.z = f2bf(v.z); pk.w = f2bf(v.w);
  *(ushort4*)(out + i) = pk;
}

// transpose+convert: in f32 [rows][cols] (slice z at in + z*inSlice)
// out[( c + z*outRowStep )*ldo + z*outColStep + r] = in[r][c]  (bf16)
__global__ void tcvt(const float* __restrict__ in, bf16_t* __restrict__ out,
                     int cols, size_t inSlice, size_t ldo,
                     int outRowStep, int outColStep) {
  __shared__ float tile[32][33];
  const int z  = blockIdx.z;
  const float* src = in + (size_t)z * inSlice;
  const int c0 = blockIdx.x * 32;
  const int r0 = blockIdx.y * 32;
  const int tx = threadIdx.x;
  const int ty = threadIdx.y;
#pragma unroll
  for (int i = 0; i < 32; i += 8)
    tile[ty + i][tx] = src[(size_t)(r0 + ty + i) * cols + (c0 + tx)];
  __syncthreads();
#pragma unroll
  for (int i = 0; i < 32; i += 8) {
    float v = tile[tx][ty + i];
    out[((size_t)(c0 + ty + i) + (size_t)z * outRowStep) * ldo +
        (size_t)z * outColStep + (r0 + tx)] = f2bf(v);
  }
}

// ---------------------------------------------------------------- routing
// ctrl layout (ints): [0..63] bin_count, [64..127] bin_fill, [128..191] bin_start,
//                     [192] n_tiles, [256 + 3t .. ] meta{gid, slot0, nrows}

__global__ void zero_ctrl(int* ctrl) {
  ctrl[blockIdx.x * 256 + threadIdx.x] = 0;   // grid 4 -> 1024 ints
}

__global__ void router_kernel(const float* __restrict__ x,
                              const float* __restrict__ rw,
                              const float* __restrict__ rb,
                              int* __restrict__ ctrl,
                              int* __restrict__ gid_tok,
                              float2* __restrict__ tokscale) {
  const int token = blockIdx.x * 4 + (threadIdx.x >> 6);
  const int lane  = threadIdx.x & 63;
  const float* xr = x + (size_t)token * HDIM;

  double acc[NEXP];
#pragma unroll
  for (int e = 0; e < NEXP; e++) acc[e] = 0.0;
  for (int h = lane; h < HDIM; h += 64) {
    double xv = (double)xr[h];
    const float* wr = rw + (size_t)h * NEXP;
#pragma unroll
    for (int e = 0; e < NEXP; e++) acc[e] += xv * (double)wr[e];
  }
#pragma unroll
  for (int off = 32; off > 0; off >>= 1) {
#pragma unroll
    for (int e = 0; e < NEXP; e++) acc[e] += __shfl_xor(acc[e], off, 64);
  }
  double lg[NEXP];
#pragma unroll
  for (int e = 0; e < NEXP; e++) lg[e] = acc[e] + (double)rb[e];

  double mx = lg[0];
#pragma unroll
  for (int e = 1; e < NEXP; e++) mx = fmax(mx, lg[e]);
  double p[NEXP]; double den = 0.0;
#pragma unroll
  for (int e = 0; e < NEXP; e++) { p[e] = exp(lg[e] - mx); den += p[e]; }

  int i1 = 0;
#pragma unroll
  for (int e = 1; e < NEXP; e++) if (lg[e] > lg[i1]) i1 = e;
  int i2 = (i1 == 0) ? 1 : 0;
#pragma unroll
  for (int e = 0; e < NEXP; e++)
    if (e != i1 && e != i2 && lg[e] > lg[i2]) i2 = e;

  if (lane == 0) {
    const int elo = min(i1, i2), ehi = max(i1, i2);
    const int gid = elo * 8 + ehi;
    gid_tok[token] = gid;
    tokscale[token] = make_float2((float)(p[elo] / den), (float)(p[ehi] / den));
    atomicAdd(&ctrl[gid], 1);
  }
}

__global__ void build_tiles(int* __restrict__ ctrl, int* __restrict__ tok_of_slot,
                            float2* __restrict__ scale_of_slot) {
  const int t = threadIdx.x;
  for (int i = t; i < MAXSLOTS; i += 256) {
    tok_of_slot[i] = -1;
    scale_of_slot[i] = make_float2(0.f, 0.f);
  }
  if (t < 64) ctrl[64 + t] = 0;  // bin_fill
  __syncthreads();
  if (t == 0) {
    int running = 0, tiles = 0;
    for (int g = 0; g < 64; g++) {
      const int c = ctrl[g];
      ctrl[128 + g] = running;
      const int nt = (c + 127) >> 7;
      for (int i = 0; i < nt; i++) {
        ctrl[256 + tiles * 3 + 0] = g;
        ctrl[256 + tiles * 3 + 1] = running + i * 128;
        ctrl[256 + tiles * 3 + 2] = min(128, c - i * 128);
        tiles++;
      }
      running += nt << 7;
    }
    ctrl[192] = tiles;
  }
}

__global__ void scatter_tokens(const int* __restrict__ gid_tok,
                               const float2* __restrict__ tokscale,
                               int* __restrict__ ctrl,
                               int* __restrict__ tok_of_slot,
                               float2* __restrict__ scale_of_slot) {
  const int t = blockIdx.x * 256 + threadIdx.x;
  const int g = gid_tok[t];
  const int pos = atomicAdd(&ctrl[64 + g], 1);
  const int slot = ctrl[128 + g] + pos;
  tok_of_slot[slot] = t;
  scale_of_slot[slot] = tokscale[t];
}

// ---------------------------------------------------------------- GEMMs
// LDS granule swizzle: logical granule q of row r lives at physical q^((r>>1)&3).
// Staging lane l therefore fetches global granule (l&3)^((l>>3)&3) of row l>>2.

// G1: Tp[slot][0..511] = xb[tok] @ w1cat(pair) * scale ; grid (4, MAXTILES)
__global__ __launch_bounds__(256)
void gemm_g1(const bf16_t* __restrict__ xb, const bf16_t* __restrict__ w1t,
             bf16_t* __restrict__ Tp, const int* __restrict__ ctrl,
             const int* __restrict__ tok_of_slot,
             const float2* __restrict__ scale_of_slot) {
  if ((int)blockIdx.y >= ctrl[192]) return;
  __shared__ bf16_t As[128 * 32];
  __shared__ bf16_t Bs[128 * 32];
  const int tid = threadIdx.x, lane = tid & 63, w = tid >> 6;
  const int gid   = ctrl[256 + blockIdx.y * 3];
  const int slot0 = ctrl[256 + blockIdx.y * 3 + 1];
  const int nt = blockIdx.x;
  const int e  = (nt < 2) ? (gid >> 3) : (gid & 7);
  const int wm = (w >> 1) * 64, wn = (w & 1) * 64;
  const int l16 = lane & 15, quad = lane >> 4;
  const int swz  = (quad ^ ((l16 >> 1) & 3)) * 8;
  const int gswz = ((lane & 3) ^ ((lane >> 3) & 3)) * 8;

  floatx4 acc[4][4];
  const floatx4 zero = {0.f, 0.f, 0.f, 0.f};
#pragma unroll
  for (int i = 0; i < 4; i++)
#pragma unroll
    for (int j = 0; j < 4; j++) acc[i][j] = zero;

  const int r1 = w * 32 + (lane >> 2);
  int tk1 = tok_of_slot[slot0 + r1];       if (tk1 < 0) tk1 = 0;
  int tk2 = tok_of_slot[slot0 + r1 + 16];  if (tk2 < 0) tk2 = 0;
  const bf16_t* ga1 = xb + (size_t)tk1 * HDIM + gswz;
  const bf16_t* ga2 = xb + (size_t)tk2 * HDIM + gswz;
  const int brow = e * 256 + (nt & 1) * 128 + r1;
  const bf16_t* gb1 = w1t + (size_t)brow * HDIM + gswz;
  const bf16_t* gb2 = gb1 + (size_t)16 * HDIM;
  bf16_t* lA0 = &As[w * 1024];
  bf16_t* lA1 = &As[w * 1024 + 512];
  bf16_t* lB0 = &Bs[w * 1024];
  bf16_t* lB1 = &Bs[w * 1024 + 512];

  for (int k0 = 0; k0 < HDIM; k0 += 32) {
    __syncthreads();
    gload16(ga1, lA0); gload16(ga2, lA1);
    gload16(gb1, lB0); gload16(gb2, lB1);
    ga1 += 32; ga2 += 32; gb1 += 32; gb2 += 32;
    __syncthreads();
    short8 af[4], bfr[4];
#pragma unroll
    for (int i = 0; i < 4; i++)
      af[i] = *(const short8*)&As[(wm + i * 16 + l16) * 32 + swz];
#pragma unroll
    for (int i = 0; i < 4; i++)
      bfr[i] = *(const short8*)&Bs[(wn + i * 16 + l16) * 32 + swz];
#pragma unroll
    for (int mi = 0; mi < 4; mi++)
#pragma unroll
      for (int ni = 0; ni < 4; ni++)
        acc[mi][ni] = __builtin_amdgcn_mfma_f32_16x16x32_bf16(
            af[mi], bfr[ni], acc[mi][ni], 0, 0, 0);
  }

#pragma unroll
  for (int mi = 0; mi < 4; mi++) {
#pragma unroll
    for (int r = 0; r < 4; r++) {
      const int srow = slot0 + wm + mi * 16 + quad * 4 + r;
      const float2 sc = scale_of_slot[srow];
      const float s = (nt < 2) ? sc.x : sc.y;
#pragma unroll
      for (int ni = 0; ni < 4; ni++) {
        const int col = nt * 128 + wn + ni * 16 + l16;
        Tp[(size_t)srow * 512 + col] = f2bf(acc[mi][ni][r] * s);
      }
    }
  }
}

// G2: Hb[tok][f] = gelu(Tp[slot] @ [w2[elo];w2[ehi]]) ; grid (32, MAXTILES)
__global__ __launch_bounds__(256)
void gemm_g2(const bf16_t* __restrict__ Tp, const bf16_t* __restrict__ w2t,
             bf16_t* __restrict__ Hb, const int* __restrict__ ctrl,
             const int* __restrict__ tok_of_slot) {
  if ((int)blockIdx.y >= ctrl[192]) return;
  __shared__ bf16_t As[128 * 32];
  __shared__ bf16_t Bs[128 * 32];
  const int tid = threadIdx.x, lane = tid & 63, w = tid >> 6;
  const int gid   = ctrl[256 + blockIdx.y * 3];
  const int slot0 = ctrl[256 + blockIdx.y * 3 + 1];
  const int n0 = blockIdx.x * 128;
  const int elo = gid >> 3, ehi = gid & 7;
  const int wm = (w >> 1) * 64, wn = (w & 1) * 64;
  const int l16 = lane & 15, quad = lane >> 4;
  const int swz  = (quad ^ ((l16 >> 1) & 3)) * 8;
  const int gswz = ((lane & 3) ^ ((lane >> 3) & 3)) * 8;

  floatx4 acc[4][4];
  const floatx4 zero = {0.f, 0.f, 0.f, 0.f};
#pragma unroll
  for (int i = 0; i < 4; i++)
#pragma unroll
    for (int j = 0; j < 4; j++) acc[i][j] = zero;

  const int r1 = w * 32 + (lane >> 2);
  const bf16_t* ga1 = Tp + (size_t)(slot0 + r1) * 512 + gswz;
  const bf16_t* ga2 = ga1 + (size_t)16 * 512;
  const int frow = n0 + r1;
  bf16_t* lA0 = &As[w * 1024];
  bf16_t* lA1 = &As[w * 1024 + 512];
  bf16_t* lB0 = &Bs[w * 1024];
  bf16_t* lB1 = &Bs[w * 1024 + 512];

#pragma unroll
  for (int h = 0; h < 2; h++) {
    const int e = h ? ehi : elo;
    const bf16_t* gb1 = w2t + (size_t)frow * 2048 + e * 256 + gswz;
    const bf16_t* gb2 = gb1 + (size_t)16 * 2048;
    for (int kk = 0; kk < 256; kk += 32) {
      __syncthreads();
      gload16(ga1, lA0); gload16(ga2, lA1);
      gload16(gb1, lB0); gload16(gb2, lB1);
      ga1 += 32; ga2 += 32; gb1 += 32; gb2 += 32;
      __syncthreads();
      short8 af[4], bfr[4];
#pragma unroll
      for (int i = 0; i < 4; i++)
        af[i] = *(const short8*)&As[(wm + i * 16 + l16) * 32 + swz];
#pragma unroll
      for (int i = 0; i < 4; i++)
        bfr[i] = *(const short8*)&Bs[(wn + i * 16 + l16) * 32 + swz];
#pragma unroll
      for (int mi = 0; mi < 4; mi++)
#pragma unroll
        for (int ni = 0; ni < 4; ni++)
          acc[mi][ni] = __builtin_amdgcn_mfma_f32_16x16x32_bf16(
              af[mi], bfr[ni], acc[mi][ni], 0, 0, 0);
    }
  }

#pragma unroll
  for (int mi = 0; mi < 4; mi++) {
#pragma unroll
    for (int r = 0; r < 4; r++) {
      const int srow = slot0 + wm + mi * 16 + quad * 4 + r;
      const int tok = tok_of_slot[srow];
      if (tok < 0) continue;
#pragma unroll
      for (int ni = 0; ni < 4; ni++) {
        const int col = n0 + wn + ni * 16 + l16;
        Hb[(size_t)tok * FDIM + col] = f2bf(gelu_erf(acc[mi][ni][r]));
      }
    }
  }
}

// G3: out = Hb @ ltw^T + bias ; 128x64 tile, 4 waves on M, acc[2][4]; grid (16,64)
__global__ __launch_bounds__(256)
void gemm_g3(const bf16_t* __restrict__ Hb, const bf16_t* __restrict__ ltw,
             float* __restrict__ out, const float* __restrict__ bias) {
  __shared__ bf16_t As[128 * 32];  // 8 KB
  __shared__ bf16_t Bs[64 * 32];   // 4 KB
  const int tid = threadIdx.x, lane = tid & 63, w = tid >> 6;
  const int m0 = blockIdx.y * 128, n0 = blockIdx.x * 64;
  const int wm = w * 32;
  const int l16 = lane & 15, quad = lane >> 4;
  const int swz  = (quad ^ ((l16 >> 1) & 3)) * 8;
  const int gswz = ((lane & 3) ^ ((lane >> 3) & 3)) * 8;

  floatx4 acc[2][4];
  const floatx4 zero = {0.f, 0.f, 0.f, 0.f};
#pragma unroll
  for (int i = 0; i < 2; i++)
#pragma unroll
    for (int j = 0; j < 4; j++) acc[i][j] = zero;

  const int r1 = w * 32 + (lane >> 2);
  const bf16_t* ga1 = Hb + (size_t)(m0 + r1) * FDIM + gswz;
  const bf16_t* ga2 = ga1 + (size_t)16 * FDIM;
  const bf16_t* gb1 = ltw + (size_t)(n0 + w * 16 + (lane >> 2)) * FDIM + gswz;
  bf16_t* lA0 = &As[w * 1024];
  bf16_t* lA1 = &As[w * 1024 + 512];
  bf16_t* lB0 = &Bs[w * 512];

  for (int k0 = 0; k0 < FDIM; k0 += 32) {
    __syncthreads();
    gload16(ga1, lA0); gload16(ga2, lA1); gload16(gb1, lB0);
    ga1 += 32; ga2 += 32; gb1 += 32;
    __syncthreads();
    short8 af[2], bfr[4];
#pragma unroll
    for (int i = 0; i < 2; i++)
      af[i] = *(const short8*)&As[(wm + i * 16 + l16) * 32 + swz];
#pragma unroll
    for (int i = 0; i < 4; i++)
      bfr[i] = *(const short8*)&Bs[(i * 16 + l16) * 32 + swz];
#pragma unroll
    for (int mi = 0; mi < 2; mi++)
#pragma unroll
      for (int ni = 0; ni < 4; ni++)
        acc[mi][ni] = __builtin_amdgcn_mfma_f32_16x16x32_bf16(
            af[mi], bfr[ni], acc[mi][ni], 0, 0, 0);
  }

#pragma unroll
  for (int mi = 0; mi < 2; mi++) {
#pragma unroll
    for (int ni = 0; ni < 4; ni++) {
      const int row = m0 + wm + mi * 16 + quad * 4;
      const int col = n0 + ni * 16 + l16;
#pragma unroll
      for (int r = 0; r < 4; r++)
        out[(size_t)(row + r) * HDIM + col] = acc[mi][ni][r] + bias[col];
    }
  }
}

// ---------------------------------------------------------------- launch

extern "C" void kernel_launch(void* const* d_in, const int* in_sizes, int n_in,
                              void* d_out, int out_size, void* d_ws, size_t ws_size,
                              hipStream_t stream) {
  const float* x   = (const float*)d_in[0];
  const float* rw  = (const float*)d_in[1];
  const float* rb  = (const float*)d_in[2];
  const float* w1  = (const float*)d_in[3];
  const float* w2  = (const float*)d_in[4];
  const float* l2w = (const float*)d_in[5];
  const float* l2b = (const float*)d_in[6];

  char* ws = (char*)d_ws;
  int*    ctrl     = (int*)   (ws + 0);          //   4 KB
  int*    gid_tok  = (int*)   (ws + 4096);       //  32 KB
  float2* tokscale = (float2*)(ws + 36864);      //  64 KB
  int*    tokslot  = (int*)   (ws + 102400);     //  64 KB
  float2* slotsc   = (float2*)(ws + 167936);     // 128 KB
  bf16_t* xb  = (bf16_t*)(ws + 1048576);         // 16.78 MB
  bf16_t* w1t = (bf16_t*)(ws + 17825792);        //  4.19 MB
  bf16_t* w2t = (bf16_t*)(ws + 22020096);        // 16.78 MB
  bf16_t* ltw = (bf16_t*)(ws + 38797312);        //  8.39 MB
  bf16_t* Tp  = (bf16_t*)(ws + 47185920);        // 16.78 MB
  bf16_t* Hb  = (bf16_t*)(ws + 63963136);        // 67.11 MB -> end 131,072,000

  // routing pipeline
  zero_ctrl<<<4, 256, 0, stream>>>(ctrl);
  router_kernel<<<TOK / 4, 256, 0, stream>>>(x, rw, rb, ctrl, gid_tok, tokscale);
  build_tiles<<<1, 256, 0, stream>>>(ctrl, tokslot, slotsc);
  scatter_tokens<<<TOK / 256, 256, 0, stream>>>(gid_tok, tokscale, ctrl, tokslot, slotsc);

  // bf16 conversions / transposes (independent of routing)
  cvt_x<<<TOK * HDIM / 1024, 256, 0, stream>>>(x, xb);
  tcvt<<<dim3(RDIM / 32, HDIM / 32, NEXP), dim3(32, 8), 0, stream>>>(
      w1, w1t, RDIM, (size_t)HDIM * RDIM, HDIM, RDIM, 0);
  tcvt<<<dim3(FDIM / 32, RDIM / 32, NEXP), dim3(32, 8), 0, stream>>>(
      w2, w2t, FDIM, (size_t)RDIM * FDIM, 2048, 0, RDIM);
  tcvt<<<dim3(HDIM / 32, FDIM / 32, 1), dim3(32, 8), 0, stream>>>(
      l2w, ltw, HDIM, 0, FDIM, 0, 0);

  // routed GEMMs + dense output GEMM
  gemm_g1<<<dim3(4, MAXTILES), 256, 0, stream>>>(xb, w1t, Tp, ctrl, tokslot, slotsc);
  gemm_g2<<<dim3(FDIM / 128, MAXTILES), 256, 0, stream>>>(Tp, w2t, Hb, ctrl, tokslot);
  gemm_g3<<<dim3(HDIM / 64, TOK / 128), 256, 0, stream>>>(Hb, ltw, (float*)d_out, l2b);
}

// Round 4
// 397.714 us; speedup vs baseline: 1.2652x; 1.1228x over previous
//
#include <hip/hip_runtime.h>
#include <math.h>

// MoE FFN, routed (top-2 pair-grouped):
//   router (f64 logits, fused x->bf16 convert) -> pair bins -> tiles
//   G1: Tp[slot,512] = X[tok] @ [w1[elo]|w1[ehi]] * (w_lo|w_hi)   128x64 BK=64
//   G2: Hb[tok,4096] = gelu(Tp[slot] @ [w2[elo];w2[ehi]])         128x128 BK=64
//   G3: out = Hb @ lin2_w^T + b                                   128x64 BK=64, XCD-M-specialized
// LDS: 64-col tiles, 16B granule swizzle  phys = logical ^ (row & 7).

using short8  = __attribute__((ext_vector_type(8))) short;
using floatx4 = __attribute__((ext_vector_type(4))) float;
typedef unsigned short bf16_t;

#define TOK   8192
#define HDIM  1024
#define RDIM  256
#define FDIM  4096
#define NEXP  8
#define MAXTILES 128
#define MAXSLOTS 16384

__device__ __forceinline__ bf16_t f2bf(float f) {
  union { float f; unsigned u; } a; a.f = f;
  unsigned u = a.u;
  return (bf16_t)((u + 0x7FFFu + ((u >> 16) & 1u)) >> 16);  // RNE
}

__device__ __forceinline__ float gelu_erf(float v) {
  return 0.5f * v * (1.0f + erff(v * 0.70710678118654752f));
}

__device__ __forceinline__ void gload16(const void* g, void* l) {
  __builtin_amdgcn_global_load_lds(
      (const __attribute__((address_space(1))) void*)g,
      (__attribute__((address_space(3))) void*)l, 16, 0, 0);
}

// ---------------------------------------------------------------- converts

// transpose+convert: in f32 [rows][cols] (slice z at in + z*inSlice)
// out[( c + z*outRowStep )*ldo + z*outColStep + r] = in[r][c]  (bf16)
__global__ void tcvt(const float* __restrict__ in, bf16_t* __restrict__ out,
                     int cols, size_t inSlice, size_t ldo,
                     int outRowStep, int outColStep) {
  __shared__ float tile[32][33];
  const int z  = blockIdx.z;
  const float* src = in + (size_t)z * inSlice;
  const int c0 = blockIdx.x * 32;
  const int r0 = blockIdx.y * 32;
  const int tx = threadIdx.x;
  const int ty = threadIdx.y;
#pragma unroll
  for (int i = 0; i < 32; i += 8)
    tile[ty + i][tx] = src[(size_t)(r0 + ty + i) * cols + (c0 + tx)];
  __syncthreads();
#pragma unroll
  for (int i = 0; i < 32; i += 8) {
    float v = tile[tx][ty + i];
    out[((size_t)(c0 + ty + i) + (size_t)z * outRowStep) * ldo +
        (size_t)z * outColStep + (r0 + tx)] = f2bf(v);
  }
}

// ---------------------------------------------------------------- routing
// ctrl ints: [0..63] bin_count, [64..127] bin_fill, [128..191] bin_start,
//            [192] n_tiles, [256 + 3t ..] meta{gid, slot0, nrows}

__global__ void zero_ctrl(int* ctrl) {
  ctrl[blockIdx.x * 256 + threadIdx.x] = 0;   // grid 4 -> 1024 ints
}

// router: f64 logits (selection-safe), writes bins/probs AND xb (bf16 of x)
__global__ void router_kernel(const float* __restrict__ x,
                              const float* __restrict__ rw,
                              const float* __restrict__ rb,
                              int* __restrict__ ctrl,
                              int* __restrict__ gid_tok,
                              float2* __restrict__ tokscale,
                              bf16_t* __restrict__ xb) {
  const int token = blockIdx.x * 4 + (threadIdx.x >> 6);
  const int lane  = threadIdx.x & 63;
  const float* xr = x + (size_t)token * HDIM;
  bf16_t* xbr = xb + (size_t)token * HDIM;

  double acc[NEXP];
#pragma unroll
  for (int e = 0; e < NEXP; e++) acc[e] = 0.0;
  for (int h = lane; h < HDIM; h += 64) {
    const float xf = xr[h];
    xbr[h] = f2bf(xf);
    const double xv = (double)xf;
    const float* wr = rw + (size_t)h * NEXP;
#pragma unroll
    for (int e = 0; e < NEXP; e++) acc[e] += xv * (double)wr[e];
  }
#pragma unroll
  for (int off = 32; off > 0; off >>= 1) {
#pragma unroll
    for (int e = 0; e < NEXP; e++) acc[e] += __shfl_xor(acc[e], off, 64);
  }
  double lg[NEXP];
#pragma unroll
  for (int e = 0; e < NEXP; e++) lg[e] = acc[e] + (double)rb[e];

  double mx = lg[0];
#pragma unroll
  for (int e = 1; e < NEXP; e++) mx = fmax(mx, lg[e]);
  double p[NEXP]; double den = 0.0;
#pragma unroll
  for (int e = 0; e < NEXP; e++) { p[e] = exp(lg[e] - mx); den += p[e]; }

  int i1 = 0;
#pragma unroll
  for (int e = 1; e < NEXP; e++) if (lg[e] > lg[i1]) i1 = e;
  int i2 = (i1 == 0) ? 1 : 0;
#pragma unroll
  for (int e = 0; e < NEXP; e++)
    if (e != i1 && e != i2 && lg[e] > lg[i2]) i2 = e;

  if (lane == 0) {
    const int elo = min(i1, i2), ehi = max(i1, i2);
    const int gid = elo * 8 + ehi;
    gid_tok[token] = gid;
    tokscale[token] = make_float2((float)(p[elo] / den), (float)(p[ehi] / den));
    atomicAdd(&ctrl[gid], 1);
  }
}

// parallel tile builder: 64-thread LDS scan instead of serial loop
__global__ void build_tiles(int* __restrict__ ctrl, int* __restrict__ tok_of_slot,
                            float2* __restrict__ scale_of_slot) {
  __shared__ int cnt[64], ntl[64];
  const int t = threadIdx.x;
  for (int i = t; i < MAXSLOTS; i += 256) {
    tok_of_slot[i] = -1;
    scale_of_slot[i] = make_float2(0.f, 0.f);
  }
  if (t < 64) {
    const int c = ctrl[t];
    cnt[t] = c;
    ntl[t] = (c + 127) >> 7;
    ctrl[64 + t] = 0;  // bin_fill
  }
  __syncthreads();
  if (t < 64) {
    int slot0 = 0, tile0 = 0;
    for (int g = 0; g < t; g++) { slot0 += ntl[g] << 7; tile0 += ntl[g]; }
    ctrl[128 + t] = slot0;
    const int nt = ntl[t], c = cnt[t];
    for (int i = 0; i < nt; i++) {
      ctrl[256 + (tile0 + i) * 3 + 0] = t;
      ctrl[256 + (tile0 + i) * 3 + 1] = slot0 + i * 128;
      ctrl[256 + (tile0 + i) * 3 + 2] = min(128, c - i * 128);
    }
    if (t == 63) ctrl[192] = tile0 + nt;
  }
}

__global__ void scatter_tokens(const int* __restrict__ gid_tok,
                               const float2* __restrict__ tokscale,
                               int* __restrict__ ctrl,
                               int* __restrict__ tok_of_slot,
                               float2* __restrict__ scale_of_slot) {
  const int t = blockIdx.x * 256 + threadIdx.x;
  const int g = gid_tok[t];
  const int pos = atomicAdd(&ctrl[64 + g], 1);
  const int slot = ctrl[128 + g] + pos;
  tok_of_slot[slot] = t;
  scale_of_slot[slot] = tokscale[t];
}

// ---------------------------------------------------------------- GEMMs
// 64-col (BK=64) LDS tiles, row stride 64 elems (128 B = 8 granules).
// phys granule = logical ^ (row & 7).
// Staging: lane l -> row l>>3 of an 8-row chunk, fetches global granule
// (l&7)^(l>>3&7); LDS dest is linear lane*16.
// Fragment read, kstep s: lane reads phys granule ((s*4+quad)^(l16&7)) of
// row (rowbase + l16)  [rowbase multiple of 16 => row&7 == l16&7].

// G1: Tp[slot][0..511] = xb[tok] @ w1cat * scale ; 128x64 tile; grid 8*MAXTILES
__global__ __launch_bounds__(256)
void gemm_g1(const bf16_t* __restrict__ xb, const bf16_t* __restrict__ w1t,
             bf16_t* __restrict__ Tp, const int* __restrict__ ctrl,
             const int* __restrict__ tok_of_slot,
             const float2* __restrict__ scale_of_slot) {
  const int b = blockIdx.x;
  const int tile = b >> 3, nt = b & 7;
  if (tile >= ctrl[192]) return;
  __shared__ bf16_t As[128 * 64];  // 16 KB
  __shared__ bf16_t Bs[64 * 64];   //  8 KB
  const int gid   = ctrl[256 + tile * 3];
  const int slot0 = ctrl[256 + tile * 3 + 1];
  const int e = (nt < 4) ? (gid >> 3) : (gid & 7);
  const int tid = threadIdx.x, lane = tid & 63, w = tid >> 6;
  const int l16 = lane & 15, quad = lane >> 4;
  const int rl = lane >> 3, gg = lane & 7;
  const int gf = (gg ^ rl) * 8;

  floatx4 acc[2][4];
  const floatx4 zero = {0.f, 0.f, 0.f, 0.f};
#pragma unroll
  for (int i = 0; i < 2; i++)
#pragma unroll
    for (int j = 0; j < 4; j++) acc[i][j] = zero;

  const bf16_t* ga[4];
#pragma unroll
  for (int c = 0; c < 4; c++) {
    int tk = tok_of_slot[slot0 + w * 32 + c * 8 + rl];
    if (tk < 0) tk = 0;
    ga[c] = xb + (size_t)tk * HDIM + gf;
  }
  const bf16_t* gb[2];
#pragma unroll
  for (int c = 0; c < 2; c++)
    gb[c] = w1t + (size_t)(e * 256 + (nt & 3) * 64 + w * 16 + c * 8 + rl) * HDIM + gf;
  bf16_t* lA = &As[w * 32 * 64];
  bf16_t* lB = &Bs[w * 16 * 64];

  for (int k0 = 0; k0 < HDIM; k0 += 64) {
    __syncthreads();
#pragma unroll
    for (int c = 0; c < 4; c++) { gload16(ga[c], lA + c * 512); ga[c] += 64; }
#pragma unroll
    for (int c = 0; c < 2; c++) { gload16(gb[c], lB + c * 512); gb[c] += 64; }
    __syncthreads();
#pragma unroll
    for (int s = 0; s < 2; s++) {
      const int pg = ((s * 4 + quad) ^ (l16 & 7)) * 8;
      short8 af[2], bfr[4];
#pragma unroll
      for (int i = 0; i < 2; i++)
        af[i] = *(const short8*)&As[(w * 32 + i * 16 + l16) * 64 + pg];
#pragma unroll
      for (int i = 0; i < 4; i++)
        bfr[i] = *(const short8*)&Bs[(i * 16 + l16) * 64 + pg];
#pragma unroll
      for (int mi = 0; mi < 2; mi++)
#pragma unroll
        for (int ni = 0; ni < 4; ni++)
          acc[mi][ni] = __builtin_amdgcn_mfma_f32_16x16x32_bf16(
              af[mi], bfr[ni], acc[mi][ni], 0, 0, 0);
    }
  }

#pragma unroll
  for (int mi = 0; mi < 2; mi++) {
#pragma unroll
    for (int r = 0; r < 4; r++) {
      const int srow = slot0 + w * 32 + mi * 16 + quad * 4 + r;
      const float2 sc = scale_of_slot[srow];
      const float s = (nt < 4) ? sc.x : sc.y;
#pragma unroll
      for (int ni = 0; ni < 4; ni++) {
        const int col = nt * 64 + ni * 16 + l16;
        Tp[(size_t)srow * 512 + col] = f2bf(acc[mi][ni][r] * s);
      }
    }
  }
}

// G2: Hb[tok][f] = gelu(Tp[slot] @ [w2[elo];w2[ehi]]) ; 128x128, BK=64
__global__ __launch_bounds__(256)
void gemm_g2(const bf16_t* __restrict__ Tp, const bf16_t* __restrict__ w2t,
             bf16_t* __restrict__ Hb, const int* __restrict__ ctrl,
             const int* __restrict__ tok_of_slot) {
  const int b = blockIdx.x;
  const int tile = b >> 5, n = b & 31;
  if (tile >= ctrl[192]) return;
  __shared__ bf16_t As[128 * 64];  // 16 KB
  __shared__ bf16_t Bs[128 * 64];  // 16 KB
  const int gid   = ctrl[256 + tile * 3];
  const int slot0 = ctrl[256 + tile * 3 + 1];
  const int n0 = n * 128;
  const int elo = gid >> 3, ehi = gid & 7;
  const int tid = threadIdx.x, lane = tid & 63, w = tid >> 6;
  const int wm = (w >> 1) * 64, wn = (w & 1) * 64;
  const int l16 = lane & 15, quad = lane >> 4;
  const int rl = lane >> 3, gg = lane & 7;
  const int gf = (gg ^ rl) * 8;

  floatx4 acc[4][4];
  const floatx4 zero = {0.f, 0.f, 0.f, 0.f};
#pragma unroll
  for (int i = 0; i < 4; i++)
#pragma unroll
    for (int j = 0; j < 4; j++) acc[i][j] = zero;

  const bf16_t* ga[4];
  const bf16_t* gbr[4];
#pragma unroll
  for (int c = 0; c < 4; c++) {
    ga[c]  = Tp + (size_t)(slot0 + w * 32 + c * 8 + rl) * 512 + gf;
    gbr[c] = w2t + (size_t)(n0 + w * 32 + c * 8 + rl) * 2048 + gf;
  }
  bf16_t* lA = &As[w * 32 * 64];
  bf16_t* lB = &Bs[w * 32 * 64];

#pragma unroll
  for (int t = 0; t < 8; t++) {
    const int e = (t < 4) ? elo : ehi;
    const int bcol = e * 256 + (t & 3) * 64;
    __syncthreads();
#pragma unroll
    for (int c = 0; c < 4; c++) { gload16(ga[c], lA + c * 512); ga[c] += 64; }
#pragma unroll
    for (int c = 0; c < 4; c++) gload16(gbr[c] + bcol, lB + c * 512);
    __syncthreads();
#pragma unroll
    for (int s = 0; s < 2; s++) {
      const int pg = ((s * 4 + quad) ^ (l16 & 7)) * 8;
      short8 af[4], bfr[4];
#pragma unroll
      for (int i = 0; i < 4; i++)
        af[i] = *(const short8*)&As[(wm + i * 16 + l16) * 64 + pg];
#pragma unroll
      for (int i = 0; i < 4; i++)
        bfr[i] = *(const short8*)&Bs[(wn + i * 16 + l16) * 64 + pg];
#pragma unroll
      for (int mi = 0; mi < 4; mi++)
#pragma unroll
        for (int ni = 0; ni < 4; ni++)
          acc[mi][ni] = __builtin_amdgcn_mfma_f32_16x16x32_bf16(
              af[mi], bfr[ni], acc[mi][ni], 0, 0, 0);
    }
  }

#pragma unroll
  for (int mi = 0; mi < 4; mi++) {
#pragma unroll
    for (int r = 0; r < 4; r++) {
      const int srow = slot0 + wm + mi * 16 + quad * 4 + r;
      const int tok = tok_of_slot[srow];
      if (tok < 0) continue;
#pragma unroll
      for (int ni = 0; ni < 4; ni++) {
        const int col = n0 + wn + ni * 16 + l16;
        Hb[(size_t)tok * FDIM + col] = f2bf(gelu_erf(acc[mi][ni][r]));
      }
    }
  }
}

// G3: out = Hb @ ltw^T + bias ; 128x64, BK=64, XCD-specialized M mapping.
// lin%8 ~ XCD; XCD k owns M-tiles [8k,8k+8) x all 16 N-tiles -> A fetched
// once per XCD into its L2 (16-way N reuse inside the XCD).
__global__ __launch_bounds__(256)
void gemm_g3(const bf16_t* __restrict__ Hb, const bf16_t* __restrict__ ltw,
             float* __restrict__ out, const float* __restrict__ bias) {
  __shared__ bf16_t As[128 * 64];  // 16 KB
  __shared__ bf16_t Bs[64 * 64];   //  8 KB
  const int b = blockIdx.x;
  const int xcd = b & 7, j = b >> 3;
  const int m0 = (xcd * 8 + (j & 7)) * 128;
  const int n0 = (j >> 3) * 64;
  const int tid = threadIdx.x, lane = tid & 63, w = tid >> 6;
  const int l16 = lane & 15, quad = lane >> 4;
  const int rl = lane >> 3, gg = lane & 7;
  const int gf = (gg ^ rl) * 8;

  floatx4 acc[2][4];
  const floatx4 zero = {0.f, 0.f, 0.f, 0.f};
#pragma unroll
  for (int i = 0; i < 2; i++)
#pragma unroll
    for (int j2 = 0; j2 < 4; j2++) acc[i][j2] = zero;

  const bf16_t* ga[4];
#pragma unroll
  for (int c = 0; c < 4; c++)
    ga[c] = Hb + (size_t)(m0 + w * 32 + c * 8 + rl) * FDIM + gf;
  const bf16_t* gb[2];
#pragma unroll
  for (int c = 0; c < 2; c++)
    gb[c] = ltw + (size_t)(n0 + w * 16 + c * 8 + rl) * FDIM + gf;
  bf16_t* lA = &As[w * 32 * 64];
  bf16_t* lB = &Bs[w * 16 * 64];

  for (int k0 = 0; k0 < FDIM; k0 += 64) {
    __syncthreads();
#pragma unroll
    for (int c = 0; c < 4; c++) { gload16(ga[c], lA + c * 512); ga[c] += 64; }
#pragma unroll
    for (int c = 0; c < 2; c++) { gload16(gb[c], lB + c * 512); gb[c] += 64; }
    __syncthreads();
#pragma unroll
    for (int s = 0; s < 2; s++) {
      const int pg = ((s * 4 + quad) ^ (l16 & 7)) * 8;
      short8 af[2], bfr[4];
#pragma unroll
      for (int i = 0; i < 2; i++)
        af[i] = *(const short8*)&As[(w * 32 + i * 16 + l16) * 64 + pg];
#pragma unroll
      for (int i = 0; i < 4; i++)
        bfr[i] = *(const short8*)&Bs[(i * 16 + l16) * 64 + pg];
#pragma unroll
      for (int mi = 0; mi < 2; mi++)
#pragma unroll
        for (int ni = 0; ni < 4; ni++)
          acc[mi][ni] = __builtin_amdgcn_mfma_f32_16x16x32_bf16(
              af[mi], bfr[ni], acc[mi][ni], 0, 0, 0);
    }
  }

#pragma unroll
  for (int mi = 0; mi < 2; mi++) {
#pragma unroll
    for (int ni = 0; ni < 4; ni++) {
      const int row = m0 + w * 32 + mi * 16 + quad * 4;
      const int col = n0 + ni * 16 + l16;
#pragma unroll
      for (int r = 0; r < 4; r++)
        out[(size_t)(row + r) * HDIM + col] = acc[mi][ni][r] + bias[col];
    }
  }
}

// ---------------------------------------------------------------- launch

extern "C" void kernel_launch(void* const* d_in, const int* in_sizes, int n_in,
                              void* d_out, int out_size, void* d_ws, size_t ws_size,
                              hipStream_t stream) {
  const float* x   = (const float*)d_in[0];
  const float* rw  = (const float*)d_in[1];
  const float* rb  = (const float*)d_in[2];
  const float* w1  = (const float*)d_in[3];
  const float* w2  = (const float*)d_in[4];
  const float* l2w = (const float*)d_in[5];
  const float* l2b = (const float*)d_in[6];

  char* ws = (char*)d_ws;
  int*    ctrl     = (int*)   (ws + 0);          //   4 KB
  int*    gid_tok  = (int*)   (ws + 4096);       //  32 KB
  float2* tokscale = (float2*)(ws + 36864);      //  64 KB
  int*    tokslot  = (int*)   (ws + 102400);     //  64 KB
  float2* slotsc   = (float2*)(ws + 167936);     // 128 KB
  bf16_t* xb  = (bf16_t*)(ws + 1048576);         // 16.78 MB
  bf16_t* w1t = (bf16_t*)(ws + 17825792);        //  4.19 MB
  bf16_t* w2t = (bf16_t*)(ws + 22020096);        // 16.78 MB
  bf16_t* ltw = (bf16_t*)(ws + 38797312);        //  8.39 MB
  bf16_t* Tp  = (bf16_t*)(ws + 47185920);        // 16.78 MB
  bf16_t* Hb  = (bf16_t*)(ws + 63963136);        // 67.11 MB -> end 131,072,000

  // routing pipeline (router also emits xb)
  zero_ctrl<<<4, 256, 0, stream>>>(ctrl);
  router_kernel<<<TOK / 4, 256, 0, stream>>>(x, rw, rb, ctrl, gid_tok, tokscale, xb);
  build_tiles<<<1, 256, 0, stream>>>(ctrl, tokslot, slotsc);
  scatter_tokens<<<TOK / 256, 256, 0, stream>>>(gid_tok, tokscale, ctrl, tokslot, slotsc);

  // weight transposes/converts
  tcvt<<<dim3(RDIM / 32, HDIM / 32, NEXP), dim3(32, 8), 0, stream>>>(
      w1, w1t, RDIM, (size_t)HDIM * RDIM, HDIM, RDIM, 0);
  tcvt<<<dim3(FDIM / 32, RDIM / 32, NEXP), dim3(32, 8), 0, stream>>>(
      w2, w2t, FDIM, (size_t)RDIM * FDIM, 2048, 0, RDIM);
  tcvt<<<dim3(HDIM / 32, FDIM / 32, 1), dim3(32, 8), 0, stream>>>(
      l2w, ltw, HDIM, 0, FDIM, 0, 0);

  // routed GEMMs + dense output GEMM
  gemm_g1<<<8 * MAXTILES, 256, 0, stream>>>(xb, w1t, Tp, ctrl, tokslot, slotsc);
  gemm_g2<<<32 * MAXTILES, 256, 0, stream>>>(Tp, w2t, Hb, ctrl, tokslot);
  gemm_g3<<<(TOK / 128) * (HDIM / 64), 256, 0, stream>>>(Hb, ltw, (float*)d_out, l2b);
}

// Round 5
// 366.226 us; speedup vs baseline: 1.3740x; 1.0860x over previous
//
#include <hip/hip_runtime.h>
#include <math.h>

// MoE FFN, routed (top-2 pair-grouped):
//   router (f64 logits, fused x->bf16) -> gid/probs ; build_tiles (LDS hist) ;
//   scatter tokens->slots
//   G1: Tp[slot,512] = X[tok] @ [w1[elo]|w1[ehi]] * (w_lo|w_hi)  128x64 BK=64
//   G2: Hb[tok,4096] = gelu(Tp[slot] @ [w2[elo];w2[ehi]])        128x128 BK=64
//   G3: out = Hb @ lin2_w^T + b                                  128x128 BK=64, XCD-M
// LDS granule swizzle: phys16B = logical ^ (row & 7). Verified 0 conflicts (r3/r4).
// XCD pinning: grid strides chosen = 0 mod 8 so A-sharing blocks land on one XCD.

using short8  = __attribute__((ext_vector_type(8))) short;
using floatx4 = __attribute__((ext_vector_type(4))) float;
typedef unsigned short bf16_t;

#define TOK   8192
#define HDIM  1024
#define RDIM  256
#define FDIM  4096
#define NEXP  8
#define MAXTILES 96
#define MAXSLOTS 16384

__device__ __forceinline__ bf16_t f2bf(float f) {
  union { float f; unsigned u; } a; a.f = f;
  unsigned u = a.u;
  return (bf16_t)((u + 0x7FFFu + ((u >> 16) & 1u)) >> 16);  // RNE
}

__device__ __forceinline__ float gelu_erf(float v) {
  return 0.5f * v * (1.0f + erff(v * 0.70710678118654752f));
}

__device__ __forceinline__ void gload16(const void* g, void* l) {
  __builtin_amdgcn_global_load_lds(
      (const __attribute__((address_space(1))) void*)g,
      (__attribute__((address_space(3))) void*)l, 16, 0, 0);
}

// ---------------------------------------------------------------- converts

// transpose+convert: in f32 [rows][cols] (slice z at in + z*inSlice)
// out[(c + z*outRowStep)*ldo + z*outColStep + r] = in[r][c]  (bf16)
// 64x64 tile, block (64,4): every wave reads 256B and writes a full 128B line.
__global__ void tcvt(const float* __restrict__ in, bf16_t* __restrict__ out,
                     int cols, size_t inSlice, size_t ldo,
                     int outRowStep, int outColStep) {
  __shared__ float tile[64][65];
  const int z  = blockIdx.z;
  const float* src = in + (size_t)z * inSlice;
  const int c0 = blockIdx.x * 64;
  const int r0 = blockIdx.y * 64;
  const int tx = threadIdx.x;  // 0..63
  const int ty = threadIdx.y;  // 0..3
#pragma unroll
  for (int i = 0; i < 64; i += 4)
    tile[ty + i][tx] = src[(size_t)(r0 + ty + i) * cols + (c0 + tx)];
  __syncthreads();
#pragma unroll
  for (int i = 0; i < 64; i += 4) {
    float v = tile[tx][ty + i];
    out[((size_t)(c0 + ty + i) + (size_t)z * outRowStep) * ldo +
        (size_t)z * outColStep + (r0 + tx)] = f2bf(v);
  }
}

// ---------------------------------------------------------------- routing
// ctrl ints: [64..127] bin_fill, [128..191] bin_start, [192] n_tiles,
//            [256 + 3t ..] meta{gid, slot0, nrows}

// router: f64 logits (selection-safe), writes gid/probs AND xb (bf16 of x)
__global__ void router_kernel(const float* __restrict__ x,
                              const float* __restrict__ rw,
                              const float* __restrict__ rb,
                              int* __restrict__ gid_tok,
                              float2* __restrict__ tokscale,
                              bf16_t* __restrict__ xb) {
  const int token = blockIdx.x * 4 + (threadIdx.x >> 6);
  const int lane  = threadIdx.x & 63;
  const float* xr = x + (size_t)token * HDIM;
  bf16_t* xbr = xb + (size_t)token * HDIM;

  double acc[NEXP];
#pragma unroll
  for (int e = 0; e < NEXP; e++) acc[e] = 0.0;
  for (int h = lane; h < HDIM; h += 64) {
    const float xf = xr[h];
    xbr[h] = f2bf(xf);
    const double xv = (double)xf;
    const float* wr = rw + (size_t)h * NEXP;
#pragma unroll
    for (int e = 0; e < NEXP; e++) acc[e] += xv * (double)wr[e];
  }
#pragma unroll
  for (int off = 32; off > 0; off >>= 1) {
#pragma unroll
    for (int e = 0; e < NEXP; e++) acc[e] += __shfl_xor(acc[e], off, 64);
  }
  double lg[NEXP];
#pragma unroll
  for (int e = 0; e < NEXP; e++) lg[e] = acc[e] + (double)rb[e];

  double mx = lg[0];
#pragma unroll
  for (int e = 1; e < NEXP; e++) mx = fmax(mx, lg[e]);
  double p[NEXP]; double den = 0.0;
#pragma unroll
  for (int e = 0; e < NEXP; e++) { p[e] = exp(lg[e] - mx); den += p[e]; }

  int i1 = 0;
#pragma unroll
  for (int e = 1; e < NEXP; e++) if (lg[e] > lg[i1]) i1 = e;
  int i2 = (i1 == 0) ? 1 : 0;
#pragma unroll
  for (int e = 0; e < NEXP; e++)
    if (e != i1 && e != i2 && lg[e] > lg[i2]) i2 = e;

  if (lane == 0) {
    const int elo = min(i1, i2), ehi = max(i1, i2);
    gid_tok[token] = elo * 8 + ehi;
    tokscale[token] = make_float2((float)(p[elo] / den), (float)(p[ehi] / den));
  }
}

// single block: LDS histogram of gids + prefix -> bin starts + tile metadata
__global__ void build_tiles(const int* __restrict__ gid_tok,
                            int* __restrict__ ctrl,
                            int* __restrict__ tok_of_slot,
                            float2* __restrict__ scale_of_slot) {
  __shared__ int hist[64], ntl[64];
  const int t = threadIdx.x;
  for (int i = t; i < MAXSLOTS; i += 256) {
    tok_of_slot[i] = -1;
    scale_of_slot[i] = make_float2(0.f, 0.f);
  }
  if (t < 64) { hist[t] = 0; }
  __syncthreads();
  for (int i = t; i < TOK; i += 256) atomicAdd(&hist[gid_tok[i]], 1);
  __syncthreads();
  if (t < 64) ntl[t] = (hist[t] + 127) >> 7;
  __syncthreads();
  if (t < 64) {
    int slot0 = 0, tile0 = 0;
    for (int g = 0; g < t; g++) { slot0 += ntl[g] << 7; tile0 += ntl[g]; }
    ctrl[64 + t] = 0;        // bin_fill
    ctrl[128 + t] = slot0;   // bin_start
    const int nt = ntl[t], c = hist[t];
    for (int i = 0; i < nt; i++) {
      ctrl[256 + (tile0 + i) * 3 + 0] = t;
      ctrl[256 + (tile0 + i) * 3 + 1] = slot0 + i * 128;
      ctrl[256 + (tile0 + i) * 3 + 2] = min(128, c - i * 128);
    }
    if (t == 63) ctrl[192] = tile0 + nt;
  }
}

__global__ void scatter_tokens(const int* __restrict__ gid_tok,
                               const float2* __restrict__ tokscale,
                               int* __restrict__ ctrl,
                               int* __restrict__ tok_of_slot,
                               float2* __restrict__ scale_of_slot) {
  const int t = blockIdx.x * 256 + threadIdx.x;
  const int g = gid_tok[t];
  const int pos = atomicAdd(&ctrl[64 + g], 1);
  const int slot = ctrl[128 + g] + pos;
  tok_of_slot[slot] = t;
  scale_of_slot[slot] = tokscale[t];
}

// ---------------------------------------------------------------- GEMMs
// 64-col (BK=64) LDS tiles, row stride 64 elems (8 granules of 16B).
// phys granule = logical ^ (row & 7).
// Staging: lane l -> row l>>3 of an 8-row chunk, global granule (l&7)^(l>>3);
// LDS dest linear lane*16. Fragment (kstep s): phys ((s*4+quad)^(l16&7)),
// row base multiple of 16 so row&7 == l16&7.

// G1: Tp[slot][0..511] = xb[tok] @ w1cat * scale ; 128x64 tile
// grid 8*MAXTILES, b = nt*MAXTILES + tile  (MAXTILES%8==0 -> XCD = tile%8)
__global__ __launch_bounds__(256)
void gemm_g1(const bf16_t* __restrict__ xb, const bf16_t* __restrict__ w1t,
             bf16_t* __restrict__ Tp, const int* __restrict__ ctrl,
             const int* __restrict__ tok_of_slot,
             const float2* __restrict__ scale_of_slot) {
  const int b = blockIdx.x;
  const int tile = b % MAXTILES, nt = b / MAXTILES;
  if (tile >= ctrl[192]) return;
  __shared__ bf16_t As[128 * 64];  // 16 KB
  __shared__ bf16_t Bs[64 * 64];   //  8 KB
  const int gid   = ctrl[256 + tile * 3];
  const int slot0 = ctrl[256 + tile * 3 + 1];
  const int e = (nt < 4) ? (gid >> 3) : (gid & 7);
  const int tid = threadIdx.x, lane = tid & 63, w = tid >> 6;
  const int l16 = lane & 15, quad = lane >> 4;
  const int rl = lane >> 3, gg = lane & 7;
  const int gf = (gg ^ rl) * 8;

  floatx4 acc[2][4];
  const floatx4 zero = {0.f, 0.f, 0.f, 0.f};
#pragma unroll
  for (int i = 0; i < 2; i++)
#pragma unroll
    for (int j = 0; j < 4; j++) acc[i][j] = zero;

  const bf16_t* ga[4];
#pragma unroll
  for (int c = 0; c < 4; c++) {
    int tk = tok_of_slot[slot0 + w * 32 + c * 8 + rl];
    if (tk < 0) tk = 0;
    ga[c] = xb + (size_t)tk * HDIM + gf;
  }
  const bf16_t* gb[2];
#pragma unroll
  for (int c = 0; c < 2; c++)
    gb[c] = w1t + (size_t)(e * 256 + (nt & 3) * 64 + w * 16 + c * 8 + rl) * HDIM + gf;
  bf16_t* lA = &As[w * 32 * 64];
  bf16_t* lB = &Bs[w * 16 * 64];

  for (int k0 = 0; k0 < HDIM; k0 += 64) {
    __syncthreads();
#pragma unroll
    for (int c = 0; c < 4; c++) { gload16(ga[c], lA + c * 512); ga[c] += 64; }
#pragma unroll
    for (int c = 0; c < 2; c++) { gload16(gb[c], lB + c * 512); gb[c] += 64; }
    __syncthreads();
#pragma unroll
    for (int s = 0; s < 2; s++) {
      const int pg = ((s * 4 + quad) ^ (l16 & 7)) * 8;
      short8 af[2], bfr[4];
#pragma unroll
      for (int i = 0; i < 2; i++)
        af[i] = *(const short8*)&As[(w * 32 + i * 16 + l16) * 64 + pg];
#pragma unroll
      for (int i = 0; i < 4; i++)
        bfr[i] = *(const short8*)&Bs[(i * 16 + l16) * 64 + pg];
#pragma unroll
      for (int mi = 0; mi < 2; mi++)
#pragma unroll
        for (int ni = 0; ni < 4; ni++)
          acc[mi][ni] = __builtin_amdgcn_mfma_f32_16x16x32_bf16(
              af[mi], bfr[ni], acc[mi][ni], 0, 0, 0);
    }
  }

#pragma unroll
  for (int mi = 0; mi < 2; mi++) {
#pragma unroll
    for (int r = 0; r < 4; r++) {
      const int srow = slot0 + w * 32 + mi * 16 + quad * 4 + r;
      const float2 sc = scale_of_slot[srow];
      const float s = (nt < 4) ? sc.x : sc.y;
#pragma unroll
      for (int ni = 0; ni < 4; ni++) {
        const int col = nt * 64 + ni * 16 + l16;
        Tp[(size_t)srow * 512 + col] = f2bf(acc[mi][ni][r] * s);
      }
    }
  }
}

// G2: Hb[tok][f] = gelu(Tp[slot] @ [w2[elo];w2[ehi]]) ; 128x128 BK=64
// grid 32*MAXTILES, b = n*MAXTILES + tile -> XCD = tile%8 (A tile L2-local)
__global__ __launch_bounds__(256)
void gemm_g2(const bf16_t* __restrict__ Tp, const bf16_t* __restrict__ w2t,
             bf16_t* __restrict__ Hb, const int* __restrict__ ctrl,
             const int* __restrict__ tok_of_slot) {
  const int b = blockIdx.x;
  const int tile = b % MAXTILES, n = b / MAXTILES;
  if (tile >= ctrl[192]) return;
  __shared__ bf16_t As[128 * 64];  // 16 KB
  __shared__ bf16_t Bs[128 * 64];  // 16 KB
  const int gid   = ctrl[256 + tile * 3];
  const int slot0 = ctrl[256 + tile * 3 + 1];
  const int n0 = n * 128;
  const int elo = gid >> 3, ehi = gid & 7;
  const int tid = threadIdx.x, lane = tid & 63, w = tid >> 6;
  const int wm = (w >> 1) * 64, wn = (w & 1) * 64;
  const int l16 = lane & 15, quad = lane >> 4;
  const int rl = lane >> 3, gg = lane & 7;
  const int gf = (gg ^ rl) * 8;

  floatx4 acc[4][4];
  const floatx4 zero = {0.f, 0.f, 0.f, 0.f};
#pragma unroll
  for (int i = 0; i < 4; i++)
#pragma unroll
    for (int j = 0; j < 4; j++) acc[i][j] = zero;

  const bf16_t* ga[4];
  const bf16_t* gbr[4];
#pragma unroll
  for (int c = 0; c < 4; c++) {
    ga[c]  = Tp + (size_t)(slot0 + w * 32 + c * 8 + rl) * 512 + gf;
    gbr[c] = w2t + (size_t)(n0 + w * 32 + c * 8 + rl) * 2048 + gf;
  }
  bf16_t* lA = &As[w * 32 * 64];
  bf16_t* lB = &Bs[w * 32 * 64];

#pragma unroll
  for (int t = 0; t < 8; t++) {
    const int e = (t < 4) ? elo : ehi;
    const int bcol = e * 256 + (t & 3) * 64;
    __syncthreads();
#pragma unroll
    for (int c = 0; c < 4; c++) { gload16(ga[c], lA + c * 512); ga[c] += 64; }
#pragma unroll
    for (int c = 0; c < 4; c++) gload16(gbr[c] + bcol, lB + c * 512);
    __syncthreads();
#pragma unroll
    for (int s = 0; s < 2; s++) {
      const int pg = ((s * 4 + quad) ^ (l16 & 7)) * 8;
      short8 af[4], bfr[4];
#pragma unroll
      for (int i = 0; i < 4; i++)
        af[i] = *(const short8*)&As[(wm + i * 16 + l16) * 64 + pg];
#pragma unroll
      for (int i = 0; i < 4; i++)
        bfr[i] = *(const short8*)&Bs[(wn + i * 16 + l16) * 64 + pg];
#pragma unroll
      for (int mi = 0; mi < 4; mi++)
#pragma unroll
        for (int ni = 0; ni < 4; ni++)
          acc[mi][ni] = __builtin_amdgcn_mfma_f32_16x16x32_bf16(
              af[mi], bfr[ni], acc[mi][ni], 0, 0, 0);
    }
  }

#pragma unroll
  for (int mi = 0; mi < 4; mi++) {
#pragma unroll
    for (int r = 0; r < 4; r++) {
      const int srow = slot0 + wm + mi * 16 + quad * 4 + r;
      const int tok = tok_of_slot[srow];
      if (tok < 0) continue;
#pragma unroll
      for (int ni = 0; ni < 4; ni++) {
        const int col = n0 + wn + ni * 16 + l16;
        Hb[(size_t)tok * FDIM + col] = f2bf(gelu_erf(acc[mi][ni][r]));
      }
    }
  }
}

// G3: out = Hb @ ltw^T + bias ; 128x128 BK=64, XCD-owned M groups.
// b: xcd=b&7, msub=(b>>3)&7, n=b>>6 ; XCD k owns M-tiles [8k,8k+8) x all N.
__global__ __launch_bounds__(256)
void gemm_g3(const bf16_t* __restrict__ Hb, const bf16_t* __restrict__ ltw,
             float* __restrict__ out, const float* __restrict__ bias) {
  __shared__ bf16_t As[128 * 64];  // 16 KB
  __shared__ bf16_t Bs[128 * 64];  // 16 KB
  const int b = blockIdx.x;
  const int m0 = ((b & 7) * 8 + ((b >> 3) & 7)) * 128;
  const int n0 = (b >> 6) * 128;
  const int tid = threadIdx.x, lane = tid & 63, w = tid >> 6;
  const int wm = (w >> 1) * 64, wn = (w & 1) * 64;
  const int l16 = lane & 15, quad = lane >> 4;
  const int rl = lane >> 3, gg = lane & 7;
  const int gf = (gg ^ rl) * 8;

  floatx4 acc[4][4];
  const floatx4 zero = {0.f, 0.f, 0.f, 0.f};
#pragma unroll
  for (int i = 0; i < 4; i++)
#pragma unroll
    for (int j = 0; j < 4; j++) acc[i][j] = zero;

  const bf16_t* ga[4];
  const bf16_t* gb[4];
#pragma unroll
  for (int c = 0; c < 4; c++) {
    ga[c] = Hb  + (size_t)(m0 + w * 32 + c * 8 + rl) * FDIM + gf;
    gb[c] = ltw + (size_t)(n0 + w * 32 + c * 8 + rl) * FDIM + gf;
  }
  bf16_t* lA = &As[w * 32 * 64];
  bf16_t* lB = &Bs[w * 32 * 64];

  for (int k0 = 0; k0 < FDIM; k0 += 64) {
    __syncthreads();
#pragma unroll
    for (int c = 0; c < 4; c++) { gload16(ga[c], lA + c * 512); ga[c] += 64; }
#pragma unroll
    for (int c = 0; c < 4; c++) { gload16(gb[c], lB + c * 512); gb[c] += 64; }
    __syncthreads();
#pragma unroll
    for (int s = 0; s < 2; s++) {
      const int pg = ((s * 4 + quad) ^ (l16 & 7)) * 8;
      short8 af[4], bfr[4];
#pragma unroll
      for (int i = 0; i < 4; i++)
        af[i] = *(const short8*)&As[(wm + i * 16 + l16) * 64 + pg];
#pragma unroll
      for (int i = 0; i < 4; i++)
        bfr[i] = *(const short8*)&Bs[(wn + i * 16 + l16) * 64 + pg];
#pragma unroll
      for (int mi = 0; mi < 4; mi++)
#pragma unroll
        for (int ni = 0; ni < 4; ni++)
          acc[mi][ni] = __builtin_amdgcn_mfma_f32_16x16x32_bf16(
              af[mi], bfr[ni], acc[mi][ni], 0, 0, 0);
    }
  }

#pragma unroll
  for (int mi = 0; mi < 4; mi++) {
#pragma unroll
    for (int ni = 0; ni < 4; ni++) {
      const int row = m0 + wm + mi * 16 + quad * 4;
      const int col = n0 + wn + ni * 16 + l16;
#pragma unroll
      for (int r = 0; r < 4; r++)
        out[(size_t)(row + r) * HDIM + col] = acc[mi][ni][r] + bias[col];
    }
  }
}

// ---------------------------------------------------------------- launch

extern "C" void kernel_launch(void* const* d_in, const int* in_sizes, int n_in,
                              void* d_out, int out_size, void* d_ws, size_t ws_size,
                              hipStream_t stream) {
  const float* x   = (const float*)d_in[0];
  const float* rw  = (const float*)d_in[1];
  const float* rb  = (const float*)d_in[2];
  const float* w1  = (const float*)d_in[3];
  const float* w2  = (const float*)d_in[4];
  const float* l2w = (const float*)d_in[5];
  const float* l2b = (const float*)d_in[6];

  char* ws = (char*)d_ws;
  int*    ctrl     = (int*)   (ws + 0);          //   4 KB
  int*    gid_tok  = (int*)   (ws + 4096);       //  32 KB
  float2* tokscale = (float2*)(ws + 36864);      //  64 KB
  int*    tokslot  = (int*)   (ws + 102400);     //  64 KB
  float2* slotsc   = (float2*)(ws + 167936);     // 128 KB
  bf16_t* xb  = (bf16_t*)(ws + 1048576);         // 16.78 MB
  bf16_t* w1t = (bf16_t*)(ws + 17825792);        //  4.19 MB
  bf16_t* w2t = (bf16_t*)(ws + 22020096);        // 16.78 MB
  bf16_t* ltw = (bf16_t*)(ws + 38797312);        //  8.39 MB
  bf16_t* Tp  = (bf16_t*)(ws + 47185920);        // 16.78 MB
  bf16_t* Hb  = (bf16_t*)(ws + 63963136);        // 67.11 MB -> end 131,072,000

  // routing pipeline (router also emits xb; no global atomics)
  router_kernel<<<TOK / 4, 256, 0, stream>>>(x, rw, rb, gid_tok, tokscale, xb);
  build_tiles<<<1, 256, 0, stream>>>(gid_tok, ctrl, tokslot, slotsc);
  scatter_tokens<<<TOK / 256, 256, 0, stream>>>(gid_tok, tokscale, ctrl, tokslot, slotsc);

  // weight transposes/converts (64x64 tiles, full-line writes)
  tcvt<<<dim3(RDIM / 64, HDIM / 64, NEXP), dim3(64, 4), 0, stream>>>(
      w1, w1t, RDIM, (size_t)HDIM * RDIM, HDIM, RDIM, 0);
  tcvt<<<dim3(FDIM / 64, RDIM / 64, NEXP), dim3(64, 4), 0, stream>>>(
      w2, w2t, FDIM, (size_t)RDIM * FDIM, 2048, 0, RDIM);
  tcvt<<<dim3(HDIM / 64, FDIM / 64, 1), dim3(64, 4), 0, stream>>>(
      l2w, ltw, HDIM, 0, FDIM, 0, 0);

  // routed GEMMs + dense output GEMM
  gemm_g1<<<8 * MAXTILES, 256, 0, stream>>>(xb, w1t, Tp, ctrl, tokslot, slotsc);
  gemm_g2<<<32 * MAXTILES, 256, 0, stream>>>(Tp, w2t, Hb, ctrl, tokslot);
  gemm_g3<<<512, 256, 0, stream>>>(Hb, ltw, (float*)d_out, l2b);
}